// Round 3
// baseline (288.990 us; speedup 1.0000x reference)
//
#include <hip/hip_runtime.h>
#include <hip/hip_bf16.h>

#define BB   32768
#define LL   1024
#define FEA  1028
#define MEM  50
#define DATE 32

typedef float  f32x4  __attribute__((ext_vector_type(4)));
typedef __bf16 bf16x8 __attribute__((ext_vector_type(8)));

__device__ __forceinline__ float wave_max(float v) {
    #pragma unroll
    for (int off = 32; off; off >>= 1) v = fmaxf(v, __shfl_xor(v, off));
    return v;
}
__device__ __forceinline__ float wave_sum(float v) {
    #pragma unroll
    for (int off = 32; off; off >>= 1) v += __shfl_xor(v, off);
    return v;
}

// ---------------- K1: fold transposed-conv into memory matrix ----------------
// wc[n*64+k] = sum_j convt_w[j] * mem_W[k][n+4-j], zero-padded k in [50,64)
__global__ void prep_wc(const float* __restrict__ convt_w,
                        const float* __restrict__ mem_W,
                        __bf16* __restrict__ wc) {
    int idx = blockIdx.x * 256 + threadIdx.x;   // 65536
    int n = idx >> 6, k = idx & 63;
    float acc = 0.f;
    if (k < MEM) {
        #pragma unroll
        for (int j = 0; j < 5; ++j)
            acc += convt_w[j] * mem_W[k * FEA + n + 4 - j];
    }
    wc[n * 64 + k] = (__bf16)acc;
}

// ---------------- K2: attention vector for every row -> ws (bf16, K=64) -----
__global__ __launch_bounds__(256) void att_kernel(
        const float* __restrict__ dv, const float* __restrict__ dW,
        __bf16* __restrict__ att_g) {
    const int lane = threadIdx.x & 63;
    const int wid  = threadIdx.x >> 6;
    int m = lane < MEM ? lane : MEM - 1;
    float dwv[DATE];
    const f32x4* dwp = (const f32x4*)(dW + m * DATE);
    #pragma unroll
    for (int c = 0; c < 8; ++c) {
        f32x4 v = dwp[c];
        #pragma unroll
        for (int j = 0; j < 4; ++j) dwv[c * 4 + j] = v[j];
    }
    for (int rr = 0; rr < 8; ++rr) {
        int b = blockIdx.x * 32 + wid * 8 + rr;
        const f32x4* dvp = (const f32x4*)(dv + (size_t)b * DATE);
        float sc = 0.f;
        #pragma unroll
        for (int c = 0; c < 8; ++c) {
            f32x4 v = dvp[c];
            #pragma unroll
            for (int j = 0; j < 4; ++j) sc += v[j] * dwv[c * 4 + j];
        }
        float scm = (lane < MEM) ? sc : -1e30f;
        float mx  = wave_max(scm);
        float e   = (lane < MEM) ? __expf(sc - mx) : 0.f;
        float s   = wave_sum(e);
        float p   = e / s;
        float d   = p - 0.0025f;
        float p2  = (d > 0.f) ? p * d / (d + 1e-12f) : 0.f;
        float s2  = wave_sum(p2) + 1e-12f;
        float att = p2 / s2;
        att_g[(size_t)b * 64 + lane] = (lane < MEM) ? (__bf16)att : (__bf16)0.f;
    }
}

// ---------------- K3: weight/bias streaming reduce over x --------------------
// block = 4 waves, wave handles 4 rows; 16 x4-loads in flight per wave.
__global__ __launch_bounds__(256) void fc_wb(
        const float* __restrict__ x,
        const float* __restrict__ fcw_w, const float* __restrict__ fcw_b,
        const float* __restrict__ fcb_w, const float* __restrict__ fcb_b,
        float* __restrict__ outtail) {
    const int lane = threadIdx.x & 63;
    const int wid  = threadIdx.x >> 6;
    const int r0   = blockIdx.x * 16 + wid * 4;
    f32x4 wv[4], bv[4];
    #pragma unroll
    for (int i = 0; i < 4; ++i) {
        int c = i * 256 + lane * 4;
        wv[i] = *(const f32x4*)(fcw_w + c);
        bv[i] = *(const f32x4*)(fcb_w + c);
    }
    f32x4 xv[4][4];
    #pragma unroll
    for (int r = 0; r < 4; ++r)
        #pragma unroll
        for (int i = 0; i < 4; ++i)
            xv[r][i] = *(const f32x4*)(x + (size_t)(r0 + r) * LL + i * 256 + lane * 4);
    #pragma unroll
    for (int r = 0; r < 4; ++r) {
        float aw = 0.f, ab = 0.f;
        #pragma unroll
        for (int i = 0; i < 4; ++i)
            #pragma unroll
            for (int j = 0; j < 4; ++j) {
                aw += xv[r][i][j] * wv[i][j];
                ab += xv[r][i][j] * bv[i][j];
            }
        #pragma unroll
        for (int off = 1; off <= 32; off <<= 1) {
            aw += __shfl_xor(aw, off);
            ab += __shfl_xor(ab, off);
        }
        if (lane == 0) {
            outtail[r0 + r]      = tanhf(aw + fcw_b[0]) * 0.5f + 1.0f;
            outtail[BB + r0 + r] = tanhf(ab + fcb_b[0]) * 0.5f;
        }
    }
}

// ---------------- K4: transposed-operand MFMA GEMM + epilogue ----------------
// C^T tiles: A = wc (m = n-dim), B = att (col = batch) -> acc regs are 4
// CONSECUTIVE n at fixed batch row -> f32x4 stores, no LDS transpose needed.
__global__ __launch_bounds__(256) void gemm_ep(
        const __bf16* __restrict__ att_g, const __bf16* __restrict__ wc,
        const float* __restrict__ wb, float* __restrict__ out) {
    const int lane = threadIdx.x & 63;
    const int wid  = threadIdx.x >> 6;
    const int cg   = lane & 15;
    const int kg   = lane >> 4;
    const int bc   = blockIdx.x & 3;       // col-block (256 cols)
    const int br   = blockIdx.x >> 2;      // row-block (32 batch rows)
    const int b0   = br * 32;
    const int n0   = bc * 256 + wid * 64;

    // B-operand frags: att rows (batch = b0 + ct*16 + cg)
    bf16x8 bfr[2][2];
    #pragma unroll
    for (int ct = 0; ct < 2; ++ct)
        #pragma unroll
        for (int h = 0; h < 2; ++h)
            bfr[ct][h] = *(const bf16x8*)(att_g + (size_t)(b0 + ct * 16 + cg) * 64 + h * 32 + kg * 8);

    float wreg[2], breg[2];
    #pragma unroll
    for (int ct = 0; ct < 2; ++ct) {
        int b = b0 + ct * 16 + cg;
        wreg[ct] = wb[b];
        breg[ct] = wb[BB + b];
    }

    #pragma unroll
    for (int nt = 0; nt < 4; ++nt) {
        int n = n0 + nt * 16 + cg;
        bf16x8 a0 = *(const bf16x8*)(wc + n * 64 + kg * 8);
        bf16x8 a1 = *(const bf16x8*)(wc + n * 64 + 32 + kg * 8);
        #pragma unroll
        for (int ct = 0; ct < 2; ++ct) {
            f32x4 acc = {0.f, 0.f, 0.f, 0.f};
            acc = __builtin_amdgcn_mfma_f32_16x16x32_bf16(a0, bfr[ct][0], acc, 0, 0, 0);
            acc = __builtin_amdgcn_mfma_f32_16x16x32_bf16(a1, bfr[ct][1], acc, 0, 0, 0);
            // D[row = n-offset kg*4+r4][col = batch cg]
            f32x4 v;
            #pragma unroll
            for (int r4 = 0; r4 < 4; ++r4)
                v[r4] = acc[r4] * wreg[ct] + breg[ct];
            int brow = b0 + ct * 16 + cg;
            *(f32x4*)(out + (size_t)brow * LL + n0 + nt * 16 + kg * 4) = v;
        }
    }
}

extern "C" void kernel_launch(void* const* d_in, const int* in_sizes, int n_in,
                              void* d_out, int out_size, void* d_ws, size_t ws_size,
                              hipStream_t stream) {
    const float* x     = (const float*)d_in[0];
    const float* dv    = (const float*)d_in[1];
    // d_in[2] = conv_w: DEAD CODE in the reference (st is overwritten by st_mem)
    const float* convt = (const float*)d_in[3];
    const float* memW  = (const float*)d_in[4];
    const float* dateW = (const float*)d_in[5];
    const float* fcww  = (const float*)d_in[6];
    const float* fcwb  = (const float*)d_in[7];
    const float* fcbw  = (const float*)d_in[8];
    const float* fcbb  = (const float*)d_in[9];
    float* out = (float*)d_out;

    __bf16* wc    = (__bf16*)d_ws;                        // 64K bf16 = 128 KB
    __bf16* att_g = (__bf16*)((char*)d_ws + 131072);      // 32768*64 bf16 = 4 MB
    float*  outtail = out + (size_t)BB * LL;              // w[32768], b[32768]

    prep_wc  <<<256,      256, 0, stream>>>(convt, memW, wc);
    att_kernel<<<BB / 32, 256, 0, stream>>>(dv, dateW, att_g);
    fc_wb    <<<BB / 16,  256, 0, stream>>>(x, fcww, fcwb, fcbw, fcbb, outtail);
    gemm_ep  <<<(BB / 32) * 4, 256, 0, stream>>>(att_g, wc, outtail, out);
}

// Round 4
// 285.731 us; speedup vs baseline: 1.0114x; 1.0114x over previous
//
#include <hip/hip_runtime.h>
#include <hip/hip_bf16.h>

#define BB   32768
#define LL   1024
#define FEA  1028
#define MEM  50
#define DATE 32

typedef float  f32x4  __attribute__((ext_vector_type(4)));
typedef __bf16 bf16x8 __attribute__((ext_vector_type(8)));

__device__ __forceinline__ float wave_max(float v) {
    #pragma unroll
    for (int off = 32; off; off >>= 1) v = fmaxf(v, __shfl_xor(v, off));
    return v;
}
__device__ __forceinline__ float wave_sum(float v) {
    #pragma unroll
    for (int off = 32; off; off >>= 1) v += __shfl_xor(v, off);
    return v;
}

// ---------------- K1: fold transposed-conv into memory matrix ----------------
// wc[n*64+k] = sum_j convt_w[j] * mem_W[k][n+4-j], zero-padded k in [50,64)
__global__ void prep_wc(const float* __restrict__ convt_w,
                        const float* __restrict__ mem_W,
                        __bf16* __restrict__ wc) {
    int idx = blockIdx.x * 256 + threadIdx.x;   // 65536
    int n = idx >> 6, k = idx & 63;
    float acc = 0.f;
    if (k < MEM) {
        #pragma unroll
        for (int j = 0; j < 5; ++j)
            acc += convt_w[j] * mem_W[k * FEA + n + 4 - j];
    }
    wc[n * 64 + k] = (__bf16)acc;
}

// ---------------- K2: fully fused main kernel --------------------------------
// 16 batch rows per block, 2048 blocks, 256 threads (4 waves).
// Phase 0: att (softmax+shrink) -> LDS (bf16, K padded to 64, row stride 80)
// Phase A: weight/bias fc reduce over x (the 128 MB read)
// Phase B: transposed-operand MFMA GEMM + epilogue (the 128 MB write, f32x4)
__global__ __launch_bounds__(256) void memconv_fused(
        const float* __restrict__ x,
        const float* __restrict__ dv,
        const float* __restrict__ dW,
        const float* __restrict__ fcw_w, const float* __restrict__ fcw_b,
        const float* __restrict__ fcb_w, const float* __restrict__ fcb_b,
        const __bf16* __restrict__ wc,
        float* __restrict__ out) {
    __shared__ __bf16 att_s[16 * 80];     // stride 80: 160 B, keeps b128 align
    __shared__ float  w_s[16], b_s[16];

    const int lane = threadIdx.x & 63;
    const int wid  = threadIdx.x >> 6;
    const int cg   = lane & 15;
    const int kg   = lane >> 4;
    const int b0   = blockIdx.x * 16;

    // ---- Phase 0: att for rows wid*4 .. wid*4+3 ----
    {
        int m = lane < MEM ? lane : MEM - 1;
        float dwv[DATE];
        const f32x4* dwp = (const f32x4*)(dW + m * DATE);
        #pragma unroll
        for (int c = 0; c < 8; ++c) {
            f32x4 v = dwp[c];
            #pragma unroll
            for (int j = 0; j < 4; ++j) dwv[c * 4 + j] = v[j];
        }
        #pragma unroll
        for (int rr = 0; rr < 4; ++rr) {
            int r = wid * 4 + rr;
            int b = b0 + r;
            const f32x4* dvp = (const f32x4*)(dv + (size_t)b * DATE);
            float sc = 0.f;
            #pragma unroll
            for (int c = 0; c < 8; ++c) {
                f32x4 v = dvp[c];
                #pragma unroll
                for (int j = 0; j < 4; ++j) sc += v[j] * dwv[c * 4 + j];
            }
            float scm = (lane < MEM) ? sc : -1e30f;
            float mx  = wave_max(scm);
            float e   = (lane < MEM) ? __expf(sc - mx) : 0.f;
            float s   = wave_sum(e);
            float p   = e / s;
            float d   = p - 0.0025f;
            float p2  = (d > 0.f) ? p * d / (d + 1e-12f) : 0.f;
            float s2  = wave_sum(p2) + 1e-12f;
            float att = p2 / s2;
            att_s[r * 80 + lane] = (lane < MEM) ? (__bf16)att : (__bf16)0.f;
        }
    }

    // ---- Phase A: weight/bias; wave handles 4 rows (16 lanes each) ----
    {
        int r = wid * 4 + kg;
        int b = b0 + r;
        float aw = 0.f, ab = 0.f;
        #pragma unroll
        for (int c = 0; c < 16; ++c) {
            int off = c * 64 + cg * 4;
            f32x4 xv = *(const f32x4*)(x + (size_t)b * LL + off);
            f32x4 wv = *(const f32x4*)(fcw_w + off);
            f32x4 bv = *(const f32x4*)(fcb_w + off);
            #pragma unroll
            for (int j = 0; j < 4; ++j) {
                aw += xv[j] * wv[j];
                ab += xv[j] * bv[j];
            }
        }
        #pragma unroll
        for (int off = 1; off <= 8; off <<= 1) {
            aw += __shfl_xor(aw, off);
            ab += __shfl_xor(ab, off);
        }
        if (cg == 0) {
            float w  = tanhf(aw + fcw_b[0]) * 0.5f + 1.0f;
            float bi = tanhf(ab + fcb_b[0]) * 0.5f;
            w_s[r] = w; b_s[r] = bi;
            out[(size_t)BB * LL + b]      = w;
            out[(size_t)BB * LL + BB + b] = bi;
        }
    }
    __syncthreads();

    // ---- Phase B: C^T-tile MFMA GEMM + epilogue, f32x4 stores ----
    // A = wc (m-dim = output cols n), B = att (cols = batch rows).
    // D[row kg*4+r4 -> n offset][col cg -> batch row]  (verified layout, R3)
    {
        bf16x8 bfr0 = *(const bf16x8*)(att_s + cg * 80 + kg * 8);
        bf16x8 bfr1 = *(const bf16x8*)(att_s + cg * 80 + 32 + kg * 8);
        float wreg = w_s[cg], breg = b_s[cg];
        float* orow = out + (size_t)(b0 + cg) * LL + wid * 256 + kg * 4;
        const __bf16* wbase = wc + (wid * 256 + cg) * 64 + kg * 8;
        #pragma unroll
        for (int nt = 0; nt < 16; ++nt) {
            bf16x8 a0 = *(const bf16x8*)(wbase + nt * 16 * 64);
            bf16x8 a1 = *(const bf16x8*)(wbase + nt * 16 * 64 + 32);
            f32x4 acc = {0.f, 0.f, 0.f, 0.f};
            acc = __builtin_amdgcn_mfma_f32_16x16x32_bf16(a0, bfr0, acc, 0, 0, 0);
            acc = __builtin_amdgcn_mfma_f32_16x16x32_bf16(a1, bfr1, acc, 0, 0, 0);
            f32x4 v;
            #pragma unroll
            for (int r4 = 0; r4 < 4; ++r4)
                v[r4] = acc[r4] * wreg + breg;
            *(f32x4*)(orow + nt * 16) = v;
        }
    }
}

extern "C" void kernel_launch(void* const* d_in, const int* in_sizes, int n_in,
                              void* d_out, int out_size, void* d_ws, size_t ws_size,
                              hipStream_t stream) {
    const float* x     = (const float*)d_in[0];
    const float* dv    = (const float*)d_in[1];
    // d_in[2] = conv_w: DEAD CODE in the reference (st is overwritten by st_mem)
    const float* convt = (const float*)d_in[3];
    const float* memW  = (const float*)d_in[4];
    const float* dateW = (const float*)d_in[5];
    const float* fcww  = (const float*)d_in[6];
    const float* fcwb  = (const float*)d_in[7];
    const float* fcbw  = (const float*)d_in[8];
    const float* fcbb  = (const float*)d_in[9];
    float* out = (float*)d_out;
    __bf16* wc = (__bf16*)d_ws;   // 64K bf16 = 128 KB

    prep_wc      <<<256,     256, 0, stream>>>(convt, memW, wc);
    memconv_fused<<<BB / 16, 256, 0, stream>>>(x, dv, dateW, fcww, fcwb, fcbw, fcbb, wc, out);
}

// Round 5
// 273.720 us; speedup vs baseline: 1.0558x; 1.0439x over previous
//
#include <hip/hip_runtime.h>
#include <hip/hip_bf16.h>

#define BB   32768
#define LL   1024
#define FEA  1028
#define MEM  50
#define DATE 32

typedef float  f32x4  __attribute__((ext_vector_type(4)));
typedef __bf16 bf16x8 __attribute__((ext_vector_type(8)));

__device__ __forceinline__ float wave_max(float v) {
    #pragma unroll
    for (int off = 32; off; off >>= 1) v = fmaxf(v, __shfl_xor(v, off));
    return v;
}
__device__ __forceinline__ float wave_sum(float v) {
    #pragma unroll
    for (int off = 32; off; off >>= 1) v += __shfl_xor(v, off);
    return v;
}

// ---------------- K1: fold transposed-conv into memory matrix ----------------
// wc[n*64+k] = sum_j convt_w[j] * mem_W[k][n+4-j], zero-padded k in [50,64)
__global__ void prep_wc(const float* __restrict__ convt_w,
                        const float* __restrict__ mem_W,
                        __bf16* __restrict__ wc) {
    int idx = blockIdx.x * 256 + threadIdx.x;   // 65536
    int n = idx >> 6, k = idx & 63;
    float acc = 0.f;
    if (k < MEM) {
        #pragma unroll
        for (int j = 0; j < 5; ++j)
            acc += convt_w[j] * mem_W[k * FEA + n + 4 - j];
    }
    wc[n * 64 + k] = (__bf16)acc;
}

// ---------------- K2: fused main kernel, contiguity-first --------------------
// 16 rows/block, 2048 blocks, 4 waves.
// Phase 0: att -> LDS. Phase A: wb via FULL-ROW contiguous loads (1KB/inst,
// 16 independent loads in flight). Phase B: MFMA -> LDS stage -> row-contiguous
// f32x4 stores (256B segments, 4/inst) in 4 rounds.
__global__ __launch_bounds__(256) void memconv_fused(
        const float* __restrict__ x,
        const float* __restrict__ dv,
        const float* __restrict__ dW,
        const float* __restrict__ fcw_w, const float* __restrict__ fcw_b,
        const float* __restrict__ fcb_w, const float* __restrict__ fcb_b,
        const __bf16* __restrict__ wc,
        float* __restrict__ out) {
    __shared__ __bf16 att_s[16 * 72];          // [row][k], 144B stride (16B-mult)
    __shared__ float  w_s[16], b_s[16];
    __shared__ float  stage[4][16 * 72];       // per-wave D staging, stride 72 f32

    const int lane = threadIdx.x & 63;
    const int wid  = threadIdx.x >> 6;
    const int cg   = lane & 15;
    const int kg   = lane >> 4;
    const int b0   = blockIdx.x * 16;

    // ---- Phase 0: att for rows wid*4 .. wid*4+3 ----
    {
        int m = lane < MEM ? lane : MEM - 1;
        float dwv[DATE];
        const f32x4* dwp = (const f32x4*)(dW + m * DATE);
        #pragma unroll
        for (int c = 0; c < 8; ++c) {
            f32x4 v = dwp[c];
            #pragma unroll
            for (int j = 0; j < 4; ++j) dwv[c * 4 + j] = v[j];
        }
        #pragma unroll
        for (int rr = 0; rr < 4; ++rr) {
            int r = wid * 4 + rr;
            const f32x4* dvp = (const f32x4*)(dv + (size_t)(b0 + r) * DATE);
            float sc = 0.f;
            #pragma unroll
            for (int c = 0; c < 8; ++c) {
                f32x4 v = dvp[c];
                #pragma unroll
                for (int j = 0; j < 4; ++j) sc += v[j] * dwv[c * 4 + j];
            }
            float scm = (lane < MEM) ? sc : -1e30f;
            float mx  = wave_max(scm);
            float e   = (lane < MEM) ? __expf(sc - mx) : 0.f;
            float s   = wave_sum(e);
            float p   = e / s;
            float d   = p - 0.0025f;
            float p2  = (d > 0.f) ? p * d / (d + 1e-12f) : 0.f;
            float s2  = wave_sum(p2) + 1e-12f;
            float att = p2 / s2;
            att_s[r * 72 + lane] = (lane < MEM) ? (__bf16)att : (__bf16)0.f;
        }
    }

    // ---- Phase A: wb, full-row contiguous loads. Wave owns rows wid*4..+3 ----
    {
        f32x4 wv[4], bv[4];
        #pragma unroll
        for (int c = 0; c < 4; ++c) {
            wv[c] = *(const f32x4*)(fcw_w + c * 256 + lane * 4);
            bv[c] = *(const f32x4*)(fcb_w + c * 256 + lane * 4);
        }
        f32x4 xv[4][4];
        #pragma unroll
        for (int rr = 0; rr < 4; ++rr)
            #pragma unroll
            for (int c = 0; c < 4; ++c)
                xv[rr][c] = *(const f32x4*)(x + (size_t)(b0 + wid * 4 + rr) * LL
                                              + c * 256 + lane * 4);
        #pragma unroll
        for (int rr = 0; rr < 4; ++rr) {
            int r = wid * 4 + rr;
            float aw = 0.f, ab = 0.f;
            #pragma unroll
            for (int c = 0; c < 4; ++c)
                #pragma unroll
                for (int j = 0; j < 4; ++j) {
                    aw += xv[rr][c][j] * wv[c][j];
                    ab += xv[rr][c][j] * bv[c][j];
                }
            #pragma unroll
            for (int off = 1; off <= 32; off <<= 1) {
                aw += __shfl_xor(aw, off);
                ab += __shfl_xor(ab, off);
            }
            float w  = tanhf(aw + fcw_b[0]) * 0.5f + 1.0f;
            float bi = tanhf(ab + fcb_b[0]) * 0.5f;
            if (lane == 0) {
                w_s[r] = w; b_s[r] = bi;
                out[(size_t)BB * LL + (b0 + r)]      = w;
                out[(size_t)BB * LL + BB + (b0 + r)] = bi;
            }
        }
    }
    __syncthreads();

    // ---- Phase B: transposed-operand MFMA + LDS-staged contiguous stores ----
    // A = wc (m = n-dim), B = att (col = batch). D[n_off kg*4+r4][batch cg].
    {
        bf16x8 bfr0 = *(const bf16x8*)(att_s + cg * 72 + kg * 8);
        bf16x8 bfr1 = *(const bf16x8*)(att_s + cg * 72 + 32 + kg * 8);
        float* st = stage[wid];
        const int n0 = wid * 256;
        #pragma unroll
        for (int R = 0; R < 4; ++R) {
            // compute 4 tiles (64 n-columns), stage D into LDS
            #pragma unroll
            for (int t = 0; t < 4; ++t) {
                int n = n0 + (R * 4 + t) * 16 + cg;
                bf16x8 a0 = *(const bf16x8*)(wc + n * 64 + kg * 8);
                bf16x8 a1 = *(const bf16x8*)(wc + n * 64 + 32 + kg * 8);
                f32x4 acc = {0.f, 0.f, 0.f, 0.f};
                acc = __builtin_amdgcn_mfma_f32_16x16x32_bf16(a0, bfr0, acc, 0, 0, 0);
                acc = __builtin_amdgcn_mfma_f32_16x16x32_bf16(a1, bfr1, acc, 0, 0, 0);
                *(f32x4*)(st + cg * 72 + t * 16 + kg * 4) = acc;
            }
            // flush: row-contiguous, 4x 256B segments per inst
            #pragma unroll
            for (int j = 0; j < 4; ++j) {
                int row = j * 4 + (lane >> 4);
                int nl  = (lane & 15) * 4;
                f32x4 v = *(const f32x4*)(st + row * 72 + nl);
                float w = w_s[row], bi = b_s[row];
                f32x4 o;
                #pragma unroll
                for (int k = 0; k < 4; ++k) o[k] = v[k] * w + bi;
                *(f32x4*)(out + (size_t)(b0 + row) * LL + n0 + R * 64 + nl) = o;
            }
        }
    }
}

extern "C" void kernel_launch(void* const* d_in, const int* in_sizes, int n_in,
                              void* d_out, int out_size, void* d_ws, size_t ws_size,
                              hipStream_t stream) {
    const float* x     = (const float*)d_in[0];
    const float* dv    = (const float*)d_in[1];
    // d_in[2] = conv_w: DEAD CODE in the reference (st is overwritten by st_mem)
    const float* convt = (const float*)d_in[3];
    const float* memW  = (const float*)d_in[4];
    const float* dateW = (const float*)d_in[5];
    const float* fcww  = (const float*)d_in[6];
    const float* fcwb  = (const float*)d_in[7];
    const float* fcbw  = (const float*)d_in[8];
    const float* fcbb  = (const float*)d_in[9];
    float* out = (float*)d_out;
    __bf16* wc = (__bf16*)d_ws;   // 64K bf16 = 128 KB

    prep_wc      <<<256,     256, 0, stream>>>(convt, memW, wc);
    memconv_fused<<<BB / 16, 256, 0, stream>>>(x, dv, dateW, fcww, fcwb, fcbw, fcbb, wc, out);
}